// Round 1
// baseline (143.123 us; speedup 1.0000x reference)
//
#include <hip/hip_runtime.h>
#include <math.h>

// Problem constants (match reference)
#define N_ATOMS 256
#define N_FEAT  128
#define BATCH   8
#define BINS    300
#define NSEG    32131          // triu_indices(255, k=2)
#define INV_STEP 149.5f        // (BINS-1)/2
#define ONE_OVER_2PI 0.15915494309189535f
#define INV_112 0.8928571428571429f   // 1/1.12
#define WIN 6                  // RBF window radius: exp(-36) ~ 2e-16, below f32 noise

// segment index: s(i,j) = offset(i) + (j - i - 2), i in [0,252], j in [i+2,254]
__device__ __forceinline__ int seg_offset(int i) { return i * 253 - (i * (i - 1)) / 2; }

struct V3 { float x, y, z; };
__device__ __forceinline__ V3 v3sub(V3 a, V3 b) { return {a.x-b.x, a.y-b.y, a.z-b.z}; }
__device__ __forceinline__ float v3dot(V3 a, V3 b) { return a.x*b.x + a.y*b.y + a.z*b.z; }
__device__ __forceinline__ V3 v3cross(V3 a, V3 b) {
    return {a.y*b.z - a.z*b.y, a.z*b.x - a.x*b.z, a.x*b.y - a.y*b.x};
}
__device__ __forceinline__ V3 v3nrm(V3 a) {
    float r = 1.0f / sqrtf(v3dot(a, a));
    return {a.x*r, a.y*r, a.z*r};
}
__device__ __forceinline__ float clamp1(float x) { return fminf(1.0f, fmaxf(-1.0f, x)); }

// ---------------- Kernel 1: writhe per (batch, segment) ----------------
// grid = (253, BATCH), block = 256. blockIdx.x = i; thread t -> j = i+2+t.
__global__ __launch_bounds__(256) void writhe_kernel(const float* __restrict__ coords,
                                                     float* __restrict__ wr_out) {
    __shared__ float cs[N_ATOMS * 3];
    const int b = blockIdx.y;
    const int i = blockIdx.x;
    for (int idx = threadIdx.x; idx < N_ATOMS * 3; idx += 256)
        cs[idx] = coords[b * N_ATOMS * 3 + idx];
    __syncthreads();

    const int t = threadIdx.x;
    const int j = i + 2 + t;
    if (j > N_ATOMS - 2) return;   // j <= 254

    auto ld = [&](int a) -> V3 { return {cs[a*3+0], cs[a*3+1], cs[a*3+2]}; };
    V3 pi = ld(i), pi1 = ld(i + 1), pj = ld(j), pj1 = ld(j + 1);

    V3 d0 = v3nrm(v3sub(pj,  pi));    // x_j   - x_i
    V3 d1 = v3nrm(v3sub(pj1, pi));    // x_j+1 - x_i
    V3 d2 = v3nrm(v3sub(pj,  pi1));   // x_j   - x_i+1
    V3 d3 = v3nrm(v3sub(pj1, pi1));   // x_j+1 - x_i+1

    V3 c0 = v3nrm(v3cross(d0, d1));
    V3 c1 = v3nrm(v3cross(d1, d3));
    V3 c2 = v3nrm(v3cross(d3, d2));
    V3 c3 = v3nrm(v3cross(d2, d0));

    float omega = asinf(clamp1(v3dot(c0, c1)))
                + asinf(clamp1(v3dot(c1, c2)))
                + asinf(clamp1(v3dot(c2, c3)))
                + asinf(clamp1(v3dot(c3, c0)));

    float sg = v3dot(v3cross(v3sub(pj1, pj), v3sub(pi1, pi)), d0);
    float sign = (sg > 0.0f) ? 1.0f : ((sg < 0.0f) ? -1.0f : 0.0f);

    wr_out[b * NSEG + seg_offset(i) + t] = omega * sign * ONE_OVER_2PI;
}

// ---------------- Kernel 2: per-node histogram + projection ----------------
// One block per node n = b*256 + t. Incoming edges of node t: a in [0, t-2];
// type-1 (start-pair, segment (a,t)) exists iff t<=254; type-2 (end-pair,
// segment (a-1,t-1)) exists iff a>=1. Both share weight g = exp(-||c_a-c_t||^2).
__device__ __forceinline__ void deposit(float* hist, float g, float wr) {
    float p = (wr + 1.0f) * INV_STEP;          // position in bin units; p - k = (wr - c_k)/STEP
    int k0 = __float2int_rn(p);
    int klo = max(0, k0 - WIN);
    int khi = min(BINS - 1, k0 + WIN);
    float d = p - (float)klo;
    float e = __expf(-d * d);                  // w_klo
    float u = __expf(2.0f * d - 1.0f);         // ratio w_{k+1}/w_k at k=klo
    const float C = 0.13533528323661270f;      // e^-2
    for (int k = klo; k <= khi; ++k) {
        atomicAdd(&hist[k], g * e);
        e *= u;
        u *= C;
    }
}

__global__ __launch_bounds__(256) void message_kernel(const float* __restrict__ coords,
                                                      const float* __restrict__ nf,
                                                      const float* __restrict__ basis,
                                                      const float* __restrict__ wr,
                                                      float* __restrict__ out) {
    const int n = blockIdx.x;
    const int b = n >> 8;
    const int t = n & 255;
    const int tid = threadIdx.x;

    if (t < 2) {  // no incoming edges: out = node_features
        if (tid < N_FEAT) out[n * N_FEAT + tid] = nf[n * N_FEAT + tid];
        return;
    }

    __shared__ float hist[BINS];
    __shared__ float sden;
    for (int k = tid; k < BINS; k += 256) hist[k] = 0.0f;
    if (tid == 0) sden = 0.0f;
    __syncthreads();

    const int na = t - 1;                    // a in [0, t-2]
    const bool e1 = (t <= N_ATOMS - 2);      // type-1 edges exist (t <= 254)
    const float ctx = coords[n * 3 + 0];
    const float cty = coords[n * 3 + 1];
    const float ctz = coords[n * 3 + 2];

    float g = 0.0f;
    float dpart = 0.0f;
    const int a = tid;
    if (a < na) {
        const int ga = ((b << 8) + a) * 3;
        float dx = coords[ga + 0] - ctx;
        float dy = coords[ga + 1] - cty;
        float dz = coords[ga + 2] - ctz;
        g = __expf(-(dx * dx + dy * dy + dz * dz));
        dpart = g * ((e1 ? 1.0f : 0.0f) + (a >= 1 ? 1.0f : 0.0f));
    }
    // denominator: wave-reduce then one LDS atomic per wave
    for (int off = 32; off > 0; off >>= 1) dpart += __shfl_down(dpart, off);
    if ((tid & 63) == 0) atomicAdd(&sden, dpart);

    if (a < na) {
        const int base = b * NSEG;
        const int col = t - a - 2;           // j - i - 2 for both segment types
        if (e1)     deposit(hist, g, wr[base + seg_offset(a) + col]);
        if (a >= 1) deposit(hist, g, wr[base + seg_offset(a - 1) + col]);
    }
    __syncthreads();

    if (tid < N_FEAT) {
        const float scale = INV_112 / sden;
        float acc = 0.0f;
        #pragma unroll 4
        for (int k = 0; k < BINS; ++k)
            acc = fmaf(hist[k], basis[k * N_FEAT + tid], acc);
        out[n * N_FEAT + tid] = nf[n * N_FEAT + tid] + acc * scale;
    }
}

extern "C" void kernel_launch(void* const* d_in, const int* in_sizes, int n_in,
                              void* d_out, int out_size, void* d_ws, size_t ws_size,
                              hipStream_t stream) {
    const float* coords = (const float*)d_in[0];   // (B*N, 3) f32
    const float* nf     = (const float*)d_in[1];   // (B*N, 128) f32
    const float* basis  = (const float*)d_in[2];   // (300, 128) f32
    float* wr  = (float*)d_ws;                     // B*NSEG floats = 1.03 MB
    float* out = (float*)d_out;                    // (B*N, 128) f32

    dim3 g1(253, BATCH);
    writhe_kernel<<<g1, 256, 0, stream>>>(coords, wr);
    message_kernel<<<BATCH * N_ATOMS, 256, 0, stream>>>(coords, nf, basis, wr, out);
}

// Round 3
// 141.810 us; speedup vs baseline: 1.0093x; 1.0093x over previous
//
#include <hip/hip_runtime.h>
#include <math.h>

// Problem constants (match reference)
#define N_ATOMS 256
#define N_FEAT  128
#define BATCH   8
#define BINS    300
#define NSEG    32131          // triu pairs of non-overlapping unit segments in 256 atoms
#define INV_STEP 149.5f        // (BINS-1)/2
#define ONE_OVER_2PI 0.15915494309189535f
#define INV_112 0.8928571428571429f   // 1/1.12
#define WIN 6                  // RBF window radius: exp(-36) ~ 2e-16, below f32 noise
#define NHIST 8                // privatized histogram copies

// Transposed segment indexing: rows by j (j in [2,254]), row j holds i = 0..j-2.
// offT(j) = (j-1)(j-2)/2. Total = offT(255) = 32131 = NSEG.
__device__ __forceinline__ int offT(int j) { return ((j - 1) * (j - 2)) >> 1; }

struct V3 { float x, y, z; };
__device__ __forceinline__ V3 v3sub(V3 a, V3 b) { return {a.x-b.x, a.y-b.y, a.z-b.z}; }
__device__ __forceinline__ float v3dot(V3 a, V3 b) { return a.x*b.x + a.y*b.y + a.z*b.z; }
__device__ __forceinline__ V3 v3cross(V3 a, V3 b) {
    return {a.y*b.z - a.z*b.y, a.z*b.x - a.x*b.z, a.x*b.y - a.y*b.x};
}
__device__ __forceinline__ V3 v3nrm(V3 a) {
    float r = __builtin_amdgcn_rsqf(v3dot(a, a));   // v_rsq_f32: fast, ~1 ulp
    return {a.x*r, a.y*r, a.z*r};
}
__device__ __forceinline__ float clamp1(float x) { return fminf(1.0f, fmaxf(-1.0f, x)); }

// ---------------- Kernel 1: writhe per (batch, segment), transposed layout ----
// grid = (253, BATCH), block = 256. blockIdx.x -> j = bx+2 (fixed per block);
// thread i in [0, j-2]. Writes wrT[b*NSEG + offT(j) + i]  (contiguous per block).
__global__ __launch_bounds__(256) void writhe_kernel(const float* __restrict__ coords,
                                                     float* __restrict__ wrT) {
    __shared__ float cs[N_ATOMS * 3];
    const int b = blockIdx.y;
    const int j = blockIdx.x + 2;
    for (int idx = threadIdx.x; idx < N_ATOMS * 3; idx += 256)
        cs[idx] = coords[b * N_ATOMS * 3 + idx];
    __syncthreads();

    const int i = threadIdx.x;
    if (i > j - 2) return;

    auto ld = [&](int a) -> V3 { return {cs[a*3+0], cs[a*3+1], cs[a*3+2]}; };
    V3 pi = ld(i), pi1 = ld(i + 1), pj = ld(j), pj1 = ld(j + 1);

    V3 d0 = v3nrm(v3sub(pj,  pi));    // x_j   - x_i
    V3 d1 = v3nrm(v3sub(pj1, pi));    // x_j+1 - x_i
    V3 d2 = v3nrm(v3sub(pj,  pi1));   // x_j   - x_i+1
    V3 d3 = v3nrm(v3sub(pj1, pi1));   // x_j+1 - x_i+1

    V3 c0 = v3nrm(v3cross(d0, d1));
    V3 c1 = v3nrm(v3cross(d1, d3));
    V3 c2 = v3nrm(v3cross(d3, d2));
    V3 c3 = v3nrm(v3cross(d2, d0));

    float omega = asinf(clamp1(v3dot(c0, c1)))
                + asinf(clamp1(v3dot(c1, c2)))
                + asinf(clamp1(v3dot(c2, c3)))
                + asinf(clamp1(v3dot(c3, c0)));

    float sg = v3dot(v3cross(v3sub(pj1, pj), v3sub(pi1, pi)), d0);
    float sign = (sg > 0.0f) ? 1.0f : ((sg < 0.0f) ? -1.0f : 0.0f);

    wrT[b * NSEG + offT(j) + i] = omega * sign * ONE_OVER_2PI;
}

// ---------------- Kernel 2: per-node histogram + projection -------------------
// One block per node n = b*256 + t. Incoming edges of node t: a in [0, t-2];
// type-1 (start-pair, segment (a,t)) exists iff t<=254; type-2 (end-pair,
// segment (a-1,t-1)) exists iff a>=1. Both share g = exp(-||c_a-c_t||^2).
// Histogram: NHIST privatized copies (copy = tid&7) + per-lane rotated window
// walk (rot = tid%13) -> same-address ds_add collisions ~eliminated.
__device__ __forceinline__ void deposit(float* h8, int copy, int rot,
                                        float g, float wr) {
    float p = (wr + 1.0f) * INV_STEP;      // p - k = (wr - c_k)/STEP
    int k0 = __float2int_rn(p);
    int klo = k0 - WIN;                    // may be < 0
    #pragma unroll
    for (int m = 0; m < 2 * WIN + 1; ++m) {
        int mm = m + rot; if (mm >= 2 * WIN + 1) mm -= 2 * WIN + 1;
        int k = klo + mm;
        if (k >= 0 && k < BINS) {
            float d = p - (float)k;
            atomicAdd(&h8[copy * BINS + k], g * __expf(-d * d));
        }
    }
}

__global__ __launch_bounds__(256) void message_kernel(const float* __restrict__ coords,
                                                      const float* __restrict__ nf,
                                                      const float* __restrict__ basis,
                                                      const float* __restrict__ wrT,
                                                      float* __restrict__ out) {
    const int n = blockIdx.x;
    const int b = n >> 8;
    const int t = n & 255;
    const int tid = threadIdx.x;

    if (t < 2) {  // no incoming edges: out = node_features
        if (tid < N_FEAT) out[n * N_FEAT + tid] = nf[n * N_FEAT + tid];
        return;
    }

    __shared__ float h8[NHIST * BINS];
    __shared__ float histF[BINS];
    __shared__ float part[256];
    __shared__ float sden;
    for (int k = tid; k < NHIST * BINS; k += 256) h8[k] = 0.0f;
    if (tid == 0) sden = 0.0f;
    __syncthreads();

    const int na = t - 1;                    // a in [0, t-2]
    const bool e1 = (t <= N_ATOMS - 2);      // type-1 edges exist (t <= 254)
    const float ctx = coords[n * 3 + 0];
    const float cty = coords[n * 3 + 1];
    const float ctz = coords[n * 3 + 2];

    float g = 0.0f;
    float dpart = 0.0f;
    const int a = tid;
    if (a < na) {
        const int ga = ((b << 8) + a) * 3;
        float dx = coords[ga + 0] - ctx;
        float dy = coords[ga + 1] - cty;
        float dz = coords[ga + 2] - ctz;
        g = __expf(-(dx * dx + dy * dy + dz * dz));
        dpart = g * ((e1 ? 1.0f : 0.0f) + (a >= 1 ? 1.0f : 0.0f));
    }
    // denominator: wave-reduce then one LDS atomic per wave
    for (int off = 32; off > 0; off >>= 1) dpart += __shfl_down(dpart, off);
    if ((tid & 63) == 0) atomicAdd(&sden, dpart);

    if (a < na) {
        const int copy = tid & (NHIST - 1);
        const int rot = tid % (2 * WIN + 1);
        const int base = b * NSEG;
        // coalesced: consecutive a -> consecutive addresses
        if (e1)     deposit(h8, copy, rot, g, wrT[base + offT(t) + a]);
        if (a >= 1) deposit(h8, copy, rot, g, wrT[base + offT(t - 1) + a - 1]);
    }
    __syncthreads();

    // reduce privatized copies -> histF
    for (int k = tid; k < BINS; k += 256) {
        float s = 0.0f;
        #pragma unroll
        for (int c = 0; c < NHIST; ++c) s += h8[c * BINS + k];
        histF[k] = s;
    }
    __syncthreads();

    // projection: all 256 threads; feat f = tid&127, bin-half h = tid>>7
    const int f = tid & (N_FEAT - 1);
    const int h = tid >> 7;
    float acc = 0.0f;
    const int kbeg = h * (BINS / 2);
    #pragma unroll 4
    for (int k = kbeg; k < kbeg + BINS / 2; ++k)
        acc = fmaf(histF[k], basis[k * N_FEAT + f], acc);
    part[tid] = acc;
    __syncthreads();

    if (tid < N_FEAT) {
        const float scale = INV_112 / sden;
        out[n * N_FEAT + tid] = nf[n * N_FEAT + tid]
                              + (part[tid] + part[tid + N_FEAT]) * scale;
    }
}

extern "C" void kernel_launch(void* const* d_in, const int* in_sizes, int n_in,
                              void* d_out, int out_size, void* d_ws, size_t ws_size,
                              hipStream_t stream) {
    const float* coords = (const float*)d_in[0];   // (B*N, 3) f32
    const float* nf     = (const float*)d_in[1];   // (B*N, 128) f32
    const float* basis  = (const float*)d_in[2];   // (300, 128) f32
    float* wrT = (float*)d_ws;                     // B*NSEG floats = 1.03 MB
    float* out = (float*)d_out;                    // (B*N, 128) f32

    dim3 g1(253, BATCH);
    writhe_kernel<<<g1, 256, 0, stream>>>(coords, wrT);
    message_kernel<<<BATCH * N_ATOMS, 256, 0, stream>>>(coords, nf, basis, wrT, out);
}